// Round 1
// baseline (1026.530 us; speedup 1.0000x reference)
//
#include <hip/hip_runtime.h>

#define NROI  2048
#define CCH   256
#define IMH   200
#define IMW   200
#define CROP  7
#define PP    49          // CROP*CROP
#define FANIN 12544       // CCH*PP
#define HID   1024

// ---------------------------------------------------------------------------
// RoIAlign: one block per ROI. crops[n][c*49+p] = bilinear(x[b,c], bin p)
// ---------------------------------------------------------------------------
__global__ __launch_bounds__(256) void roi_align_kernel(
    const float* __restrict__ x, const float* __restrict__ rois,
    float* __restrict__ crops)
{
    const int n   = blockIdx.x;
    const int tid = threadIdx.x;

    __shared__ int   s_x0[PP], s_y0[PP], s_x1[PP], s_y1[PP];
    __shared__ float s_wx[PP], s_wy[PP];
    __shared__ int   s_b;

    if (tid == 0) s_b = (int)rois[(size_t)n * 5 + 0];
    if (tid < PP) {
        const float rx1 = rois[(size_t)n * 5 + 1];
        const float ry1 = rois[(size_t)n * 5 + 2];
        const float rx2 = rois[(size_t)n * 5 + 3];
        const float ry2 = rois[(size_t)n * 5 + 4];
        const float bw = (rx2 - rx1) / 7.0f;
        const float bh = (ry2 - ry1) / 7.0f;
        const int pi = tid / 7;            // row -> y
        const int pj = tid - pi * 7;       // col -> x
        // match reference op order (no fma contraction): rx1 + c*bw
        float px = __fadd_rn(rx1, __fmul_rn((float)pj + 0.5f, bw));
        float py = __fadd_rn(ry1, __fmul_rn((float)pi + 0.5f, bh));
        px = fminf(fmaxf(px, 0.0f), (float)(IMW - 1));
        py = fminf(fmaxf(py, 0.0f), (float)(IMH - 1));
        const float fx = floorf(px), fy = floorf(py);
        const int x0 = (int)fx, y0 = (int)fy;
        s_x0[tid] = x0;
        s_y0[tid] = y0;
        s_x1[tid] = min(x0 + 1, IMW - 1);
        s_y1[tid] = min(y0 + 1, IMH - 1);
        s_wx[tid] = px - fx;
        s_wy[tid] = py - fy;
    }
    __syncthreads();

    const float* xb   = x + (size_t)s_b * (CCH * IMH * IMW);
    float*       crow = crops + (size_t)n * FANIN;

    for (int i = tid; i < FANIN; i += 256) {
        const int c = i / PP;
        const int p = i - c * PP;
        const float* xc = xb + (size_t)c * (IMH * IMW);
        const int x0 = s_x0[p], x1 = s_x1[p], y0 = s_y0[p], y1 = s_y1[p];
        const float wx = s_wx[p], wy = s_wy[p];
        const float v00 = xc[y0 * IMW + x0];
        const float v01 = xc[y0 * IMW + x1];
        const float v10 = xc[y1 * IMW + x0];
        const float v11 = xc[y1 * IMW + x1];
        const float top = v00 + wx * (v01 - v00);
        const float bot = v10 + wx * (v11 - v10);
        crow[i] = top + wy * (bot - top);
    }
}

// ---------------------------------------------------------------------------
// f32 NT GEMM: C[M,N] partial = A[M,K] * B[N,K]^T, K split in 2 via blockIdx.z
// BM=BN=128, BK=16, 256 threads, 8x8 micro-tile (split quadrants).
// ---------------------------------------------------------------------------
__global__ __launch_bounds__(256) void gemm_nt_128(
    const float* __restrict__ A, const float* __restrict__ Bw,
    float* __restrict__ P0, float* __restrict__ P1,
    int M, int N, int K)
{
    __shared__ float As[16][132];   // [k][m], pad->all LDS ops <=2-way
    __shared__ float Bs[16][132];

    const int tid = threadIdx.x;
    const int tx = tid & 15;        // 16 cols of threads
    const int ty = tid >> 4;        // 16 rows of threads
    const int bm = blockIdx.y * 128;
    const int bn = blockIdx.x * 128;
    const int kHalf = K >> 1;
    const int kBase = blockIdx.z * kHalf;

    const float* At = A  + (size_t)bm * K + kBase;
    const float* Bt = Bw + (size_t)bn * K + kBase;

    const int r0 = tid >> 2;          // 0..63
    const int kq = (tid & 3) * 4;     // 0,4,8,12

    float acc[8][8];
#pragma unroll
    for (int i = 0; i < 8; ++i)
#pragma unroll
        for (int j = 0; j < 8; ++j) acc[i][j] = 0.0f;

    for (int kt = 0; kt < kHalf; kt += 16) {
        const float4 a0 = *(const float4*)(At + (size_t)r0        * K + kt + kq);
        const float4 a1 = *(const float4*)(At + (size_t)(r0 + 64) * K + kt + kq);
        const float4 b0 = *(const float4*)(Bt + (size_t)r0        * K + kt + kq);
        const float4 b1 = *(const float4*)(Bt + (size_t)(r0 + 64) * K + kt + kq);

        __syncthreads();   // previous iteration's reads done
        As[kq + 0][r0] = a0.x; As[kq + 1][r0] = a0.y;
        As[kq + 2][r0] = a0.z; As[kq + 3][r0] = a0.w;
        As[kq + 0][r0 + 64] = a1.x; As[kq + 1][r0 + 64] = a1.y;
        As[kq + 2][r0 + 64] = a1.z; As[kq + 3][r0 + 64] = a1.w;
        Bs[kq + 0][r0] = b0.x; Bs[kq + 1][r0] = b0.y;
        Bs[kq + 2][r0] = b0.z; Bs[kq + 3][r0] = b0.w;
        Bs[kq + 0][r0 + 64] = b1.x; Bs[kq + 1][r0 + 64] = b1.y;
        Bs[kq + 2][r0 + 64] = b1.z; Bs[kq + 3][r0 + 64] = b1.w;
        __syncthreads();

#pragma unroll
        for (int k = 0; k < 16; ++k) {
            const float4 alo = *(const float4*)&As[k][ty * 4];
            const float4 ahi = *(const float4*)&As[k][64 + ty * 4];
            const float4 blo = *(const float4*)&Bs[k][tx * 4];
            const float4 bhi = *(const float4*)&Bs[k][64 + tx * 4];
            const float ar[8] = {alo.x, alo.y, alo.z, alo.w, ahi.x, ahi.y, ahi.z, ahi.w};
            const float br[8] = {blo.x, blo.y, blo.z, blo.w, bhi.x, bhi.y, bhi.z, bhi.w};
#pragma unroll
            for (int i = 0; i < 8; ++i)
#pragma unroll
                for (int j = 0; j < 8; ++j)
                    acc[i][j] = fmaf(ar[i], br[j], acc[i][j]);
        }
    }

    float* P = blockIdx.z ? P1 : P0;
#pragma unroll
    for (int ih = 0; ih < 2; ++ih)
#pragma unroll
        for (int i = 0; i < 4; ++i) {
            const int ri  = ih * 4 + i;
            const int row = bm + ih * 64 + ty * 4 + i;
            float4 v0 = make_float4(acc[ri][0], acc[ri][1], acc[ri][2], acc[ri][3]);
            float4 v1 = make_float4(acc[ri][4], acc[ri][5], acc[ri][6], acc[ri][7]);
            *(float4*)(P + (size_t)row * N + bn + tx * 4)      = v0;
            *(float4*)(P + (size_t)row * N + bn + 64 + tx * 4) = v1;
        }
}

// ---------------------------------------------------------------------------
// h = relu(P0 + P1 + bias), N=1024 columns
// ---------------------------------------------------------------------------
__global__ __launch_bounds__(256) void combine_relu(
    const float* __restrict__ P0, const float* __restrict__ P1,
    const float* __restrict__ bias, float* __restrict__ H)
{
    const int g = blockIdx.x * 256 + threadIdx.x;          // float4 index
    const float4 p0 = ((const float4*)P0)[g];
    const float4 p1 = ((const float4*)P1)[g];
    const int col = (g & 255) * 4;                         // HID=1024 -> 256 float4/row
    const float4 bv = *(const float4*)(bias + col);
    float4 r;
    r.x = fmaxf(p0.x + p1.x + bv.x, 0.0f);
    r.y = fmaxf(p0.y + p1.y + bv.y, 0.0f);
    r.z = fmaxf(p0.z + p1.z + bv.z, 0.0f);
    r.w = fmaxf(p0.w + p1.w + bv.w, 0.0f);
    ((float4*)H)[g] = r;
}

// ---------------------------------------------------------------------------
// heads: out[m*2+o] (o<2, wc/bc) and out[4096 + m*8 + (o-2)] (wb/bb)
// ---------------------------------------------------------------------------
__global__ __launch_bounds__(256) void heads_kernel(
    const float* __restrict__ h2,
    const float* __restrict__ wc, const float* __restrict__ bc,
    const float* __restrict__ wb, const float* __restrict__ bb,
    float* __restrict__ out)
{
    const int g = blockIdx.x * 256 + threadIdx.x;   // 20480 total
    const int m = g / 10;
    const int o = g - m * 10;
    const float* hrow = h2 + (size_t)m * HID;
    const float* wrow;
    float bias;
    if (o < 2) { wrow = wc + (size_t)o * HID;       bias = bc[o];     }
    else       { wrow = wb + (size_t)(o - 2) * HID; bias = bb[o - 2]; }
    float acc = 0.0f;
#pragma unroll 4
    for (int k = 0; k < HID; k += 4) {
        const float4 h4 = *(const float4*)(hrow + k);
        const float4 w4 = *(const float4*)(wrow + k);
        acc += h4.x * w4.x + h4.y * w4.y + h4.z * w4.z + h4.w * w4.w;
    }
    const float v = acc + bias;
    if (o < 2) out[m * 2 + o] = v;
    else       out[NROI * 2 + m * 8 + (o - 2)] = v;
}

// ---------------------------------------------------------------------------
extern "C" void kernel_launch(void* const* d_in, const int* in_sizes, int n_in,
                              void* d_out, int out_size, void* d_ws, size_t ws_size,
                              hipStream_t stream)
{
    const float* x    = (const float*)d_in[0];
    const float* rois = (const float*)d_in[1];
    const float* w1   = (const float*)d_in[2];
    const float* b1   = (const float*)d_in[3];
    const float* w2   = (const float*)d_in[4];
    const float* b2   = (const float*)d_in[5];
    const float* wc   = (const float*)d_in[6];
    const float* bc   = (const float*)d_in[7];
    const float* wb   = (const float*)d_in[8];
    const float* bb   = (const float*)d_in[9];
    float* out = (float*)d_out;

    char* ws = (char*)d_ws;
    const size_t CROPS_B = (size_t)NROI * FANIN * 4;   // 102,760,448
    const size_t HBUF_B  = (size_t)NROI * HID * 4;     //   8,388,608
    float* crops = (float*)(ws);
    float* p0    = (float*)(ws + CROPS_B);
    float* p1    = (float*)(ws + CROPS_B + HBUF_B);
    float* h1    = (float*)(ws + CROPS_B + 2 * HBUF_B);
    float* h2    = (float*)(ws + CROPS_B + 3 * HBUF_B);

    // 1. RoIAlign
    roi_align_kernel<<<NROI, 256, 0, stream>>>(x, rois, crops);

    // 2. FC1: [2048,12544] x [1024,12544]^T  (K-split 2)
    gemm_nt_128<<<dim3(HID / 128, NROI / 128, 2), 256, 0, stream>>>(
        crops, w1, p0, p1, NROI, HID, FANIN);
    combine_relu<<<(NROI * HID / 4) / 256, 256, 0, stream>>>(p0, p1, b1, h1);

    // 3. FC2: [2048,1024] x [1024,1024]^T  (K-split 2)
    gemm_nt_128<<<dim3(HID / 128, NROI / 128, 2), 256, 0, stream>>>(
        h1, w2, p0, p1, NROI, HID, HID);
    combine_relu<<<(NROI * HID / 4) / 256, 256, 0, stream>>>(p0, p1, b2, h2);

    // 4. heads
    heads_kernel<<<(NROI * 10) / 256, 256, 0, stream>>>(h2, wc, bc, wb, bb, out);
}

// Round 2
// 554.621 us; speedup vs baseline: 1.8509x; 1.8509x over previous
//
#include <hip/hip_runtime.h>

#define NROI  2048
#define CCH   256
#define IMH   200
#define IMW   200
#define CROP  7
#define PP    49
#define FANIN 12544
#define HID   1024

typedef __attribute__((ext_vector_type(8))) short bf16x8;
typedef __attribute__((ext_vector_type(4))) float f32x4;

__device__ __forceinline__ unsigned short bf16_rne(float f) {
    unsigned u = __float_as_uint(f);
    u = (u + 0x7FFFu + ((u >> 16) & 1u)) >> 16;
    return (unsigned short)u;
}
__device__ __forceinline__ float bf16_to_f32(unsigned short h) {
    return __uint_as_float((unsigned)h << 16);
}

__device__ __forceinline__ void gload16(const void* g, void* l) {
    __builtin_amdgcn_global_load_lds(
        (const __attribute__((address_space(1))) void*)g,
        (__attribute__((address_space(3))) void*)l, 16, 0, 0);
}

// ---------------------------------------------------------------------------
// RoIAlign -> hi/lo bf16 crops. One block per ROI.
// ---------------------------------------------------------------------------
__global__ __launch_bounds__(256) void roi_align_kernel(
    const float* __restrict__ x, const float* __restrict__ rois,
    unsigned short* __restrict__ cropsH, unsigned short* __restrict__ cropsL)
{
    const int n   = blockIdx.x;
    const int tid = threadIdx.x;

    __shared__ int   s_x0[PP], s_y0[PP], s_x1[PP], s_y1[PP];
    __shared__ float s_wx[PP], s_wy[PP];
    __shared__ int   s_b;

    if (tid == 0) s_b = (int)rois[(size_t)n * 5 + 0];
    if (tid < PP) {
        const float rx1 = rois[(size_t)n * 5 + 1];
        const float ry1 = rois[(size_t)n * 5 + 2];
        const float rx2 = rois[(size_t)n * 5 + 3];
        const float ry2 = rois[(size_t)n * 5 + 4];
        const float bw = (rx2 - rx1) / 7.0f;
        const float bh = (ry2 - ry1) / 7.0f;
        const int pi = tid / 7;
        const int pj = tid - pi * 7;
        float px = __fadd_rn(rx1, __fmul_rn((float)pj + 0.5f, bw));
        float py = __fadd_rn(ry1, __fmul_rn((float)pi + 0.5f, bh));
        px = fminf(fmaxf(px, 0.0f), (float)(IMW - 1));
        py = fminf(fmaxf(py, 0.0f), (float)(IMH - 1));
        const float fx = floorf(px), fy = floorf(py);
        const int x0 = (int)fx, y0 = (int)fy;
        s_x0[tid] = x0;
        s_y0[tid] = y0;
        s_x1[tid] = min(x0 + 1, IMW - 1);
        s_y1[tid] = min(y0 + 1, IMH - 1);
        s_wx[tid] = px - fx;
        s_wy[tid] = py - fy;
    }
    __syncthreads();

    const float* xb = x + (size_t)s_b * (CCH * IMH * IMW);
    const size_t rowoff = (size_t)n * FANIN;

    for (int i = tid; i < FANIN; i += 256) {
        const int c = i / PP;
        const int p = i - c * PP;
        const float* xc = xb + (size_t)c * (IMH * IMW);
        const int x0 = s_x0[p], x1 = s_x1[p], y0 = s_y0[p], y1 = s_y1[p];
        const float wx = s_wx[p], wy = s_wy[p];
        const float v00 = xc[y0 * IMW + x0];
        const float v01 = xc[y0 * IMW + x1];
        const float v10 = xc[y1 * IMW + x0];
        const float v11 = xc[y1 * IMW + x1];
        const float top = v00 + wx * (v01 - v00);
        const float bot = v10 + wx * (v11 - v10);
        const float val = top + wy * (bot - top);
        const unsigned short h = bf16_rne(val);
        const unsigned short l = bf16_rne(val - bf16_to_f32(h));
        cropsH[rowoff + i] = h;
        cropsL[rowoff + i] = l;
    }
}

// ---------------------------------------------------------------------------
// f32 -> (hi, lo) bf16 split, vectorized.
// ---------------------------------------------------------------------------
__global__ __launch_bounds__(256) void convert_split(
    const float* __restrict__ w, unsigned short* __restrict__ wH,
    unsigned short* __restrict__ wL, int n4)
{
    for (int g = blockIdx.x * 256 + threadIdx.x; g < n4; g += gridDim.x * 256) {
        const float4 v = ((const float4*)w)[g];
        unsigned short h0 = bf16_rne(v.x), h1 = bf16_rne(v.y),
                       h2 = bf16_rne(v.z), h3 = bf16_rne(v.w);
        unsigned short l0 = bf16_rne(v.x - bf16_to_f32(h0));
        unsigned short l1 = bf16_rne(v.y - bf16_to_f32(h1));
        unsigned short l2 = bf16_rne(v.z - bf16_to_f32(h2));
        unsigned short l3 = bf16_rne(v.w - bf16_to_f32(h3));
        ((uint2*)wH)[g] = make_uint2((unsigned)h0 | ((unsigned)h1 << 16),
                                     (unsigned)h2 | ((unsigned)h3 << 16));
        ((uint2*)wL)[g] = make_uint2((unsigned)l0 | ((unsigned)l1 << 16),
                                     (unsigned)l2 | ((unsigned)l3 << 16));
    }
}

// ---------------------------------------------------------------------------
// Split-bf16 MFMA GEMM (NT): P[z] = A[M,K] * B[N,K]^T over K-slice z.
// C ~= Ah*Bh + Al*Bh + Ah*Bl.  128x128 tile, BK=32, 4 waves of 64x64.
// LDS k-slot XOR swizzle: slot_lds = slot_g ^ ((row>>1)&3)  (16B slots).
// ---------------------------------------------------------------------------
__global__ __launch_bounds__(256, 2) void gemm3_bf16(
    const unsigned short* __restrict__ Ah, const unsigned short* __restrict__ Al,
    const unsigned short* __restrict__ Bh, const unsigned short* __restrict__ Bl,
    float* __restrict__ P, int M, int N, int K)
{
    __shared__ unsigned short lds[4][128][32];   // Ah, Al, Bh, Bl tiles (8KB each)

    const int tid  = threadIdx.x;
    const int wave = tid >> 6;
    const int lane = tid & 63;
    const int bm = blockIdx.y * 128;
    const int bn = blockIdx.x * 128;
    const int kLen  = K / gridDim.z;
    const int kBase = blockIdx.z * kLen;
    const int wr = wave >> 1, wc = wave & 1;

    f32x4 acc[4][4];
#pragma unroll
    for (int i = 0; i < 4; ++i)
#pragma unroll
        for (int j = 0; j < 4; ++j) acc[i][j] = (f32x4){0.f, 0.f, 0.f, 0.f};

    // ---- staging addressing (pre-swizzled global source) ----
    const int r_st = wave * 32 + (lane >> 2);                 // tile row, chunk 0
    const int s_st = ((lane & 3) ^ ((lane >> 3) & 3)) * 8;    // swizzled k-elem offset
    const unsigned short* gA0 = Ah + (size_t)(bm + r_st) * K + kBase + s_st;
    const unsigned short* gA1 = Al + (size_t)(bm + r_st) * K + kBase + s_st;
    const unsigned short* gB0 = Bh + (size_t)(bn + r_st) * K + kBase + s_st;
    const unsigned short* gB1 = Bl + (size_t)(bn + r_st) * K + kBase + s_st;
    const size_t rstep = (size_t)16 * K;                      // +16 rows
    unsigned short* lA0 = &lds[0][wave * 32][0];
    unsigned short* lA1 = &lds[1][wave * 32][0];
    unsigned short* lB0 = &lds[2][wave * 32][0];
    unsigned short* lB1 = &lds[3][wave * 32][0];

    // ---- fragment read addressing ----
    const int li = lane & 15;
    const int sw = (((li >> 1) & 3) ^ (lane >> 4)) * 8;       // swizzled slot

    for (int kt = 0; kt < kLen; kt += 32) {
        gload16(gA0 + kt, lA0);  gload16(gA0 + kt + rstep, lA0 + 16 * 32);
        gload16(gA1 + kt, lA1);  gload16(gA1 + kt + rstep, lA1 + 16 * 32);
        gload16(gB0 + kt, lB0);  gload16(gB0 + kt + rstep, lB0 + 16 * 32);
        gload16(gB1 + kt, lB1);  gload16(gB1 + kt + rstep, lB1 + 16 * 32);
        __syncthreads();

        bf16x8 ah[4], al[4], bh[4], bl[4];
#pragma unroll
        for (int m = 0; m < 4; ++m) {
            const int r = wr * 64 + m * 16 + li;
            ah[m] = *(const bf16x8*)&lds[0][r][sw];
            al[m] = *(const bf16x8*)&lds[1][r][sw];
        }
#pragma unroll
        for (int n = 0; n < 4; ++n) {
            const int r = wc * 64 + n * 16 + li;
            bh[n] = *(const bf16x8*)&lds[2][r][sw];
            bl[n] = *(const bf16x8*)&lds[3][r][sw];
        }
#pragma unroll
        for (int m = 0; m < 4; ++m)
#pragma unroll
            for (int n = 0; n < 4; ++n) {
                acc[m][n] = __builtin_amdgcn_mfma_f32_16x16x32_bf16(ah[m], bh[n], acc[m][n], 0, 0, 0);
                acc[m][n] = __builtin_amdgcn_mfma_f32_16x16x32_bf16(al[m], bh[n], acc[m][n], 0, 0, 0);
                acc[m][n] = __builtin_amdgcn_mfma_f32_16x16x32_bf16(ah[m], bl[n], acc[m][n], 0, 0, 0);
            }
        __syncthreads();
    }

    float* Pz = P + (size_t)blockIdx.z * M * N;
#pragma unroll
    for (int m = 0; m < 4; ++m)
#pragma unroll
        for (int n = 0; n < 4; ++n) {
            const int col = bn + wc * 64 + n * 16 + li;
#pragma unroll
            for (int e = 0; e < 4; ++e) {
                const int row = bm + wr * 64 + m * 16 + (lane >> 4) * 4 + e;
                Pz[(size_t)row * N + col] = acc[m][n][e];
            }
        }
}

// ---------------------------------------------------------------------------
// relu(p0+p1+bias) -> hi/lo bf16 (for FC1 output feeding FC2)
// ---------------------------------------------------------------------------
__global__ __launch_bounds__(256) void combine_relu_split(
    const float* __restrict__ P0, const float* __restrict__ P1,
    const float* __restrict__ bias,
    unsigned short* __restrict__ HH, unsigned short* __restrict__ HL)
{
    const int g = blockIdx.x * 256 + threadIdx.x;
    const float4 p0 = ((const float4*)P0)[g];
    const float4 p1 = ((const float4*)P1)[g];
    const float4 bv = *(const float4*)(bias + (g & 255) * 4);
    const float v0 = fmaxf(p0.x + p1.x + bv.x, 0.0f);
    const float v1 = fmaxf(p0.y + p1.y + bv.y, 0.0f);
    const float v2 = fmaxf(p0.z + p1.z + bv.z, 0.0f);
    const float v3 = fmaxf(p0.w + p1.w + bv.w, 0.0f);
    unsigned short h0 = bf16_rne(v0), h1 = bf16_rne(v1), h2 = bf16_rne(v2), h3 = bf16_rne(v3);
    unsigned short l0 = bf16_rne(v0 - bf16_to_f32(h0));
    unsigned short l1 = bf16_rne(v1 - bf16_to_f32(h1));
    unsigned short l2 = bf16_rne(v2 - bf16_to_f32(h2));
    unsigned short l3 = bf16_rne(v3 - bf16_to_f32(h3));
    ((uint2*)HH)[g] = make_uint2((unsigned)h0 | ((unsigned)h1 << 16),
                                 (unsigned)h2 | ((unsigned)h3 << 16));
    ((uint2*)HL)[g] = make_uint2((unsigned)l0 | ((unsigned)l1 << 16),
                                 (unsigned)l2 | ((unsigned)l3 << 16));
}

// ---------------------------------------------------------------------------
// relu(p0+p1+bias) -> f32 (FC2 output; may alias P0 elementwise)
// ---------------------------------------------------------------------------
__global__ __launch_bounds__(256) void combine_relu_f32(
    const float* __restrict__ P0, const float* __restrict__ P1,
    const float* __restrict__ bias, float* __restrict__ H)
{
    const int g = blockIdx.x * 256 + threadIdx.x;
    const float4 p0 = ((const float4*)P0)[g];
    const float4 p1 = ((const float4*)P1)[g];
    const float4 bv = *(const float4*)(bias + (g & 255) * 4);
    float4 r;
    r.x = fmaxf(p0.x + p1.x + bv.x, 0.0f);
    r.y = fmaxf(p0.y + p1.y + bv.y, 0.0f);
    r.z = fmaxf(p0.z + p1.z + bv.z, 0.0f);
    r.w = fmaxf(p0.w + p1.w + bv.w, 0.0f);
    ((float4*)H)[g] = r;
}

// ---------------------------------------------------------------------------
// heads: out[m*2+o] (wc/bc), out[4096 + m*8 + o'] (wb/bb). K=1024, f32.
// ---------------------------------------------------------------------------
__global__ __launch_bounds__(256) void heads_kernel(
    const float* __restrict__ h2,
    const float* __restrict__ wc, const float* __restrict__ bc,
    const float* __restrict__ wb, const float* __restrict__ bb,
    float* __restrict__ out)
{
    const int g = blockIdx.x * 256 + threadIdx.x;
    const int m = g / 10;
    const int o = g - m * 10;
    const float* hrow = h2 + (size_t)m * HID;
    const float* wrow;
    float bias;
    if (o < 2) { wrow = wc + (size_t)o * HID;       bias = bc[o];     }
    else       { wrow = wb + (size_t)(o - 2) * HID; bias = bb[o - 2]; }
    float acc = 0.0f;
#pragma unroll 4
    for (int k = 0; k < HID; k += 4) {
        const float4 h4 = *(const float4*)(hrow + k);
        const float4 w4 = *(const float4*)(wrow + k);
        acc += h4.x * w4.x + h4.y * w4.y + h4.z * w4.z + h4.w * w4.w;
    }
    const float v = acc + bias;
    if (o < 2) out[m * 2 + o] = v;
    else       out[NROI * 2 + m * 8 + (o - 2)] = v;
}

// ---------------------------------------------------------------------------
extern "C" void kernel_launch(void* const* d_in, const int* in_sizes, int n_in,
                              void* d_out, int out_size, void* d_ws, size_t ws_size,
                              hipStream_t stream)
{
    const float* x    = (const float*)d_in[0];
    const float* rois = (const float*)d_in[1];
    const float* w1   = (const float*)d_in[2];
    const float* b1   = (const float*)d_in[3];
    const float* w2   = (const float*)d_in[4];
    const float* b2   = (const float*)d_in[5];
    const float* wc   = (const float*)d_in[6];
    const float* bc   = (const float*)d_in[7];
    const float* wb   = (const float*)d_in[8];
    const float* bb   = (const float*)d_in[9];
    float* out = (float*)d_out;

    char* ws = (char*)d_ws;
    const size_t CHL = (size_t)NROI * FANIN * 2;     // 51,380,224  (crops hi / lo)
    const size_t W1S = (size_t)HID * FANIN * 2;      // 25,690,112
    const size_t W2S = (size_t)HID * HID * 2;        //  2,097,152
    const size_t PB  = (size_t)NROI * HID * 4;       //  8,388,608
    const size_t HB  = (size_t)NROI * HID * 2;       //  4,194,304

    unsigned short* cropsH = (unsigned short*)(ws);
    unsigned short* cropsL = (unsigned short*)(ws + CHL);
    unsigned short* w1H    = (unsigned short*)(ws + 2 * CHL);
    unsigned short* w1L    = (unsigned short*)(ws + 2 * CHL + W1S);
    unsigned short* w2H    = (unsigned short*)(ws + 2 * CHL + 2 * W1S);
    unsigned short* w2L    = (unsigned short*)(ws + 2 * CHL + 2 * W1S + W2S);
    float*          p0     = (float*)(ws + 2 * CHL + 2 * W1S + 2 * W2S);
    float*          p1     = (float*)(ws + 2 * CHL + 2 * W1S + 2 * W2S + PB);
    unsigned short* h1H    = (unsigned short*)(ws + 2 * CHL + 2 * W1S + 2 * W2S + 2 * PB);
    unsigned short* h1L    = (unsigned short*)(ws + 2 * CHL + 2 * W1S + 2 * W2S + 2 * PB + HB);
    float*          h2     = p0;   // elementwise alias (combine reads p0[i], writes h2[i])

    // weight splits
    convert_split<<<2048, 256, 0, stream>>>(w1, w1H, w1L, HID * FANIN / 4);
    convert_split<<<1024, 256, 0, stream>>>(w2, w2H, w2L, HID * HID / 4);

    // RoIAlign -> split crops
    roi_align_kernel<<<NROI, 256, 0, stream>>>(x, rois, cropsH, cropsL);

    // FC1
    gemm3_bf16<<<dim3(HID / 128, NROI / 128, 2), 256, 0, stream>>>(
        cropsH, cropsL, w1H, w1L, p0, NROI, HID, FANIN);
    combine_relu_split<<<(NROI * HID / 4) / 256, 256, 0, stream>>>(p0, p1, b1, h1H, h1L);

    // FC2
    gemm3_bf16<<<dim3(HID / 128, NROI / 128, 2), 256, 0, stream>>>(
        h1H, h1L, w2H, w2L, p0, NROI, HID, HID);
    combine_relu_f32<<<(NROI * HID / 4) / 256, 256, 0, stream>>>(p0, p1, b2, h2);

    // heads
    heads_kernel<<<(NROI * 10) / 256, 256, 0, stream>>>(h2, wc, bc, wb, bb, out);
}

// Round 3
// 464.565 us; speedup vs baseline: 2.2097x; 1.1938x over previous
//
#include <hip/hip_runtime.h>

#define NROI  2048
#define CCH   256
#define IMH   200
#define IMW   200
#define CROP  7
#define PP    49
#define FANIN 12544
#define HID   1024

typedef __attribute__((ext_vector_type(8))) short bf16x8;
typedef __attribute__((ext_vector_type(4))) float f32x4;

__device__ __forceinline__ unsigned short bf16_rne(float f) {
    unsigned u = __float_as_uint(f);
    u = (u + 0x7FFFu + ((u >> 16) & 1u)) >> 16;
    return (unsigned short)u;
}
__device__ __forceinline__ float bf16_to_f32(unsigned short h) {
    return __uint_as_float((unsigned)h << 16);
}

__device__ __forceinline__ void gload16(const void* g, void* l) {
    __builtin_amdgcn_global_load_lds(
        (const __attribute__((address_space(1))) void*)g,
        (__attribute__((address_space(3))) void*)l, 16, 0, 0);
}

// ---------------------------------------------------------------------------
// RoIAlign -> hi/lo bf16 crops. One block per ROI.
// ---------------------------------------------------------------------------
__global__ __launch_bounds__(256) void roi_align_kernel(
    const float* __restrict__ x, const float* __restrict__ rois,
    unsigned short* __restrict__ cropsH, unsigned short* __restrict__ cropsL)
{
    const int n   = blockIdx.x;
    const int tid = threadIdx.x;

    __shared__ int   s_x0[PP], s_y0[PP], s_x1[PP], s_y1[PP];
    __shared__ float s_wx[PP], s_wy[PP];
    __shared__ int   s_b;

    if (tid == 0) s_b = (int)rois[(size_t)n * 5 + 0];
    if (tid < PP) {
        const float rx1 = rois[(size_t)n * 5 + 1];
        const float ry1 = rois[(size_t)n * 5 + 2];
        const float rx2 = rois[(size_t)n * 5 + 3];
        const float ry2 = rois[(size_t)n * 5 + 4];
        const float bw = (rx2 - rx1) / 7.0f;
        const float bh = (ry2 - ry1) / 7.0f;
        const int pi = tid / 7;
        const int pj = tid - pi * 7;
        float px = __fadd_rn(rx1, __fmul_rn((float)pj + 0.5f, bw));
        float py = __fadd_rn(ry1, __fmul_rn((float)pi + 0.5f, bh));
        px = fminf(fmaxf(px, 0.0f), (float)(IMW - 1));
        py = fminf(fmaxf(py, 0.0f), (float)(IMH - 1));
        const float fx = floorf(px), fy = floorf(py);
        const int x0 = (int)fx, y0 = (int)fy;
        s_x0[tid] = x0;
        s_y0[tid] = y0;
        s_x1[tid] = min(x0 + 1, IMW - 1);
        s_y1[tid] = min(y0 + 1, IMH - 1);
        s_wx[tid] = px - fx;
        s_wy[tid] = py - fy;
    }
    __syncthreads();

    const float* xb = x + (size_t)s_b * (CCH * IMH * IMW);
    const size_t rowoff = (size_t)n * FANIN;

    // i = c*49 + p; stride 256 = 5*49 + 11 -> incremental carry, no idiv
    int c = tid / PP;
    int p = tid - c * PP;
    for (int i = tid; i < FANIN; i += 256) {
        const float* xc = xb + c * (IMH * IMW);
        const int x0 = s_x0[p], x1 = s_x1[p], y0 = s_y0[p], y1 = s_y1[p];
        const float wx = s_wx[p], wy = s_wy[p];
        const float v00 = xc[y0 * IMW + x0];
        const float v01 = xc[y0 * IMW + x1];
        const float v10 = xc[y1 * IMW + x0];
        const float v11 = xc[y1 * IMW + x1];
        const float top = v00 + wx * (v01 - v00);
        const float bot = v10 + wx * (v11 - v10);
        const float val = top + wy * (bot - top);
        const unsigned short h = bf16_rne(val);
        const unsigned short l = bf16_rne(val - bf16_to_f32(h));
        cropsH[rowoff + i] = h;
        cropsL[rowoff + i] = l;
        p += 11; c += 5;
        if (p >= PP) { p -= PP; ++c; }
    }
}

// ---------------------------------------------------------------------------
// f32 -> (hi, lo) bf16 split, vectorized.
// ---------------------------------------------------------------------------
__global__ __launch_bounds__(256) void convert_split(
    const float* __restrict__ w, unsigned short* __restrict__ wH,
    unsigned short* __restrict__ wL, int n4)
{
    for (int g = blockIdx.x * 256 + threadIdx.x; g < n4; g += gridDim.x * 256) {
        const float4 v = ((const float4*)w)[g];
        unsigned short h0 = bf16_rne(v.x), h1 = bf16_rne(v.y),
                       h2 = bf16_rne(v.z), h3 = bf16_rne(v.w);
        unsigned short l0 = bf16_rne(v.x - bf16_to_f32(h0));
        unsigned short l1 = bf16_rne(v.y - bf16_to_f32(h1));
        unsigned short l2 = bf16_rne(v.z - bf16_to_f32(h2));
        unsigned short l3 = bf16_rne(v.w - bf16_to_f32(h3));
        ((uint2*)wH)[g] = make_uint2((unsigned)h0 | ((unsigned)h1 << 16),
                                     (unsigned)h2 | ((unsigned)h3 << 16));
        ((uint2*)wL)[g] = make_uint2((unsigned)l0 | ((unsigned)l1 << 16),
                                     (unsigned)l2 | ((unsigned)l3 << 16));
    }
}

// ---------------------------------------------------------------------------
// Split-bf16 MFMA GEMM (NT): P[z] = A[M,K] * B[N,K]^T over K-slice z.
// C ~= Ah*Bh + Al*Bh + Ah*Bl.  128x128 tile, BK=32, 4 waves of 64x64.
// blockIdx.x = n-block (8 values) -> flat%8 pins each weight strip to one XCD.
// ---------------------------------------------------------------------------
__global__ __launch_bounds__(256, 4) void gemm3_bf16(
    const unsigned short* __restrict__ Ah, const unsigned short* __restrict__ Al,
    const unsigned short* __restrict__ Bh, const unsigned short* __restrict__ Bl,
    float* __restrict__ P, int M, int N, int K, int kLen)
{
    __shared__ unsigned short lds[4][128][32];   // Ah, Al, Bh, Bl tiles (8KB each)

    const int tid  = threadIdx.x;
    const int wave = tid >> 6;
    const int lane = tid & 63;
    const int bm = blockIdx.y * 128;
    const int bn = blockIdx.x * 128;
    const int kBase = blockIdx.z * kLen;
    const int wr = wave >> 1, wc = wave & 1;

    f32x4 acc[4][4];
#pragma unroll
    for (int i = 0; i < 4; ++i)
#pragma unroll
        for (int j = 0; j < 4; ++j) acc[i][j] = (f32x4){0.f, 0.f, 0.f, 0.f};

    // ---- staging addressing (pre-swizzled global source) ----
    const int r_st = wave * 32 + (lane >> 2);                 // tile row, chunk 0
    const int s_st = ((lane & 3) ^ ((lane >> 3) & 3)) * 8;    // swizzled k-elem offset
    const unsigned short* gA0 = Ah + (size_t)(bm + r_st) * K + kBase + s_st;
    const unsigned short* gA1 = Al + (size_t)(bm + r_st) * K + kBase + s_st;
    const unsigned short* gB0 = Bh + (size_t)(bn + r_st) * K + kBase + s_st;
    const unsigned short* gB1 = Bl + (size_t)(bn + r_st) * K + kBase + s_st;
    const size_t rstep = (size_t)16 * K;                      // +16 rows
    unsigned short* lA0 = &lds[0][wave * 32][0];
    unsigned short* lA1 = &lds[1][wave * 32][0];
    unsigned short* lB0 = &lds[2][wave * 32][0];
    unsigned short* lB1 = &lds[3][wave * 32][0];

    // ---- fragment read addressing ----
    const int li = lane & 15;
    const int sw = (((li >> 1) & 3) ^ (lane >> 4)) * 8;       // swizzled slot

    for (int kt = 0; kt < kLen; kt += 32) {
        gload16(gA0 + kt, lA0);  gload16(gA0 + kt + rstep, lA0 + 16 * 32);
        gload16(gA1 + kt, lA1);  gload16(gA1 + kt + rstep, lA1 + 16 * 32);
        gload16(gB0 + kt, lB0);  gload16(gB0 + kt + rstep, lB0 + 16 * 32);
        gload16(gB1 + kt, lB1);  gload16(gB1 + kt + rstep, lB1 + 16 * 32);
        __syncthreads();

        bf16x8 ah[4], al[4], bh[4], bl[4];
#pragma unroll
        for (int m = 0; m < 4; ++m) {
            const int r = wr * 64 + m * 16 + li;
            ah[m] = *(const bf16x8*)&lds[0][r][sw];
            al[m] = *(const bf16x8*)&lds[1][r][sw];
        }
#pragma unroll
        for (int n = 0; n < 4; ++n) {
            const int r = wc * 64 + n * 16 + li;
            bh[n] = *(const bf16x8*)&lds[2][r][sw];
            bl[n] = *(const bf16x8*)&lds[3][r][sw];
        }
#pragma unroll
        for (int m = 0; m < 4; ++m)
#pragma unroll
            for (int n = 0; n < 4; ++n) {
                acc[m][n] = __builtin_amdgcn_mfma_f32_16x16x32_bf16(ah[m], bh[n], acc[m][n], 0, 0, 0);
                acc[m][n] = __builtin_amdgcn_mfma_f32_16x16x32_bf16(al[m], bh[n], acc[m][n], 0, 0, 0);
                acc[m][n] = __builtin_amdgcn_mfma_f32_16x16x32_bf16(ah[m], bl[n], acc[m][n], 0, 0, 0);
            }
        __syncthreads();
    }

    float* Pz = P + (size_t)blockIdx.z * M * N;
#pragma unroll
    for (int m = 0; m < 4; ++m)
#pragma unroll
        for (int n = 0; n < 4; ++n) {
            const int col = bn + wc * 64 + n * 16 + li;
#pragma unroll
            for (int e = 0; e < 4; ++e) {
                const int row = bm + wr * 64 + m * 16 + (lane >> 4) * 4 + e;
                Pz[(size_t)row * N + col] = acc[m][n][e];
            }
        }
}

// ---------------------------------------------------------------------------
// relu(sum_z P[z] + bias) -> hi/lo bf16
// ---------------------------------------------------------------------------
__global__ __launch_bounds__(256) void combine_relu_split(
    const float* __restrict__ P, int Z, const float* __restrict__ bias,
    unsigned short* __restrict__ HH, unsigned short* __restrict__ HL)
{
    const int g = blockIdx.x * 256 + threadIdx.x;
    const size_t MN4 = (size_t)NROI * HID / 4;
    float4 s = ((const float4*)P)[g];
    for (int z = 1; z < Z; ++z) {
        const float4 p = ((const float4*)P)[z * MN4 + g];
        s.x += p.x; s.y += p.y; s.z += p.z; s.w += p.w;
    }
    const float4 bv = *(const float4*)(bias + (g & 255) * 4);
    const float v0 = fmaxf(s.x + bv.x, 0.0f);
    const float v1 = fmaxf(s.y + bv.y, 0.0f);
    const float v2 = fmaxf(s.z + bv.z, 0.0f);
    const float v3 = fmaxf(s.w + bv.w, 0.0f);
    unsigned short h0 = bf16_rne(v0), h1 = bf16_rne(v1), h2 = bf16_rne(v2), h3 = bf16_rne(v3);
    unsigned short l0 = bf16_rne(v0 - bf16_to_f32(h0));
    unsigned short l1 = bf16_rne(v1 - bf16_to_f32(h1));
    unsigned short l2 = bf16_rne(v2 - bf16_to_f32(h2));
    unsigned short l3 = bf16_rne(v3 - bf16_to_f32(h3));
    ((uint2*)HH)[g] = make_uint2((unsigned)h0 | ((unsigned)h1 << 16),
                                 (unsigned)h2 | ((unsigned)h3 << 16));
    ((uint2*)HL)[g] = make_uint2((unsigned)l0 | ((unsigned)l1 << 16),
                                 (unsigned)l2 | ((unsigned)l3 << 16));
}

// ---------------------------------------------------------------------------
// relu(sum_z P[z] + bias) -> f32 (writes onto P[0] elementwise - safe alias)
// ---------------------------------------------------------------------------
__global__ __launch_bounds__(256) void combine_relu_f32(
    const float* __restrict__ P, int Z, const float* __restrict__ bias,
    float* __restrict__ H)
{
    const int g = blockIdx.x * 256 + threadIdx.x;
    const size_t MN4 = (size_t)NROI * HID / 4;
    float4 s = ((const float4*)P)[g];
    for (int z = 1; z < Z; ++z) {
        const float4 p = ((const float4*)P)[z * MN4 + g];
        s.x += p.x; s.y += p.y; s.z += p.z; s.w += p.w;
    }
    const float4 bv = *(const float4*)(bias + (g & 255) * 4);
    float4 r;
    r.x = fmaxf(s.x + bv.x, 0.0f);
    r.y = fmaxf(s.y + bv.y, 0.0f);
    r.z = fmaxf(s.z + bv.z, 0.0f);
    r.w = fmaxf(s.w + bv.w, 0.0f);
    ((float4*)H)[g] = r;
}

// ---------------------------------------------------------------------------
// heads
// ---------------------------------------------------------------------------
__global__ __launch_bounds__(256) void heads_kernel(
    const float* __restrict__ h2,
    const float* __restrict__ wc, const float* __restrict__ bc,
    const float* __restrict__ wb, const float* __restrict__ bb,
    float* __restrict__ out)
{
    const int g = blockIdx.x * 256 + threadIdx.x;
    const int m = g / 10;
    const int o = g - m * 10;
    const float* hrow = h2 + (size_t)m * HID;
    const float* wrow;
    float bias;
    if (o < 2) { wrow = wc + (size_t)o * HID;       bias = bc[o];     }
    else       { wrow = wb + (size_t)(o - 2) * HID; bias = bb[o - 2]; }
    float acc = 0.0f;
#pragma unroll 4
    for (int k = 0; k < HID; k += 4) {
        const float4 h4 = *(const float4*)(hrow + k);
        const float4 w4 = *(const float4*)(wrow + k);
        acc += h4.x * w4.x + h4.y * w4.y + h4.z * w4.z + h4.w * w4.w;
    }
    const float v = acc + bias;
    if (o < 2) out[m * 2 + o] = v;
    else       out[NROI * 2 + m * 8 + (o - 2)] = v;
}

// ---------------------------------------------------------------------------
extern "C" void kernel_launch(void* const* d_in, const int* in_sizes, int n_in,
                              void* d_out, int out_size, void* d_ws, size_t ws_size,
                              hipStream_t stream)
{
    const float* x    = (const float*)d_in[0];
    const float* rois = (const float*)d_in[1];
    const float* w1   = (const float*)d_in[2];
    const float* b1   = (const float*)d_in[3];
    const float* w2   = (const float*)d_in[4];
    const float* b2   = (const float*)d_in[5];
    const float* wc   = (const float*)d_in[6];
    const float* bc   = (const float*)d_in[7];
    const float* wb   = (const float*)d_in[8];
    const float* bb   = (const float*)d_in[9];
    float* out = (float*)d_out;

    char* ws = (char*)d_ws;
    const size_t CHL = (size_t)NROI * FANIN * 2;     // 51,380,224 per array
    const size_t W1S = (size_t)HID * FANIN * 2;      // 25,690,112 per array
    const size_t W2S = (size_t)HID * HID * 2;        //  2,097,152 per array
    const size_t PB  = (size_t)NROI * HID * 4;       //  8,388,608 per z-slice
    const size_t HB  = (size_t)NROI * HID * 2;       //  4,194,304 per array

    const size_t base = 2 * CHL + 2 * W1S + 2 * W2S; // 158,334,976

    // choose K-split from available workspace: base + Z*PB + 2*HB <= ws_size
    int Z = 1;
    for (int cand = 8; cand >= 1; cand >>= 1)
        if (base + (size_t)cand * PB + 2 * HB <= ws_size) { Z = cand; break; }

    unsigned short* cropsH = (unsigned short*)(ws);
    unsigned short* cropsL = (unsigned short*)(ws + CHL);
    unsigned short* w1H    = (unsigned short*)(ws + 2 * CHL);
    unsigned short* w1L    = (unsigned short*)(ws + 2 * CHL + W1S);
    unsigned short* w2H    = (unsigned short*)(ws + 2 * CHL + 2 * W1S);
    unsigned short* w2L    = (unsigned short*)(ws + 2 * CHL + 2 * W1S + W2S);
    float*          P      = (float*)(ws + base);
    unsigned short* h1H    = (unsigned short*)(ws + base + (size_t)Z * PB);
    unsigned short* h1L    = (unsigned short*)(ws + base + (size_t)Z * PB + HB);
    float*          h2     = P;   // elementwise alias with P[0] in combine

    // weight splits
    convert_split<<<2048, 256, 0, stream>>>(w1, w1H, w1L, HID * FANIN / 4);
    convert_split<<<1024, 256, 0, stream>>>(w2, w2H, w2L, HID * HID / 4);

    // RoIAlign -> split crops
    roi_align_kernel<<<NROI, 256, 0, stream>>>(x, rois, cropsH, cropsL);

    // FC1: K = 12544, kLen = K/Z
    gemm3_bf16<<<dim3(HID / 128, NROI / 128, Z), 256, 0, stream>>>(
        cropsH, cropsL, w1H, w1L, P, NROI, HID, FANIN, FANIN / Z);
    combine_relu_split<<<(NROI * HID / 4) / 256, 256, 0, stream>>>(P, Z, b1, h1H, h1L);

    // FC2: K = 1024
    gemm3_bf16<<<dim3(HID / 128, NROI / 128, Z), 256, 0, stream>>>(
        h1H, h1L, w2H, w2L, P, NROI, HID, HID, HID / Z);
    combine_relu_f32<<<(NROI * HID / 4) / 256, 256, 0, stream>>>(P, Z, b2, h2);

    // heads
    heads_kernel<<<(NROI * 10) / 256, 256, 0, stream>>>(h2, wc, bc, wb, bb, out);
}

// Round 4
// 319.156 us; speedup vs baseline: 3.2164x; 1.4556x over previous
//
#include <hip/hip_runtime.h>

#define NROI  2048
#define CCH   256
#define IMH   200
#define IMW   200
#define CROP  7
#define PP    49
#define FANIN 12544
#define HID   1024

typedef _Float16 f16x8 __attribute__((ext_vector_type(8)));
typedef _Float16 f16x4 __attribute__((ext_vector_type(4)));
typedef _Float16 f16x2 __attribute__((ext_vector_type(2)));
typedef __attribute__((ext_vector_type(4))) float f32x4;

__device__ __forceinline__ void gload16(const void* g, void* l) {
    __builtin_amdgcn_global_load_lds(
        (const __attribute__((address_space(1))) void*)g,
        (__attribute__((address_space(3))) void*)l, 16, 0, 0);
}

// ---------------------------------------------------------------------------
// RoIAlign -> f16 crops. One block per ROI; each thread handles an i-pair.
// ---------------------------------------------------------------------------
__global__ __launch_bounds__(256) void roi_align_kernel(
    const float* __restrict__ x, const float* __restrict__ rois,
    _Float16* __restrict__ crops)
{
    const int n   = blockIdx.x;
    const int tid = threadIdx.x;

    __shared__ int   s_x0[PP], s_y0[PP], s_x1[PP], s_y1[PP];
    __shared__ float s_wx[PP], s_wy[PP];
    __shared__ int   s_b;

    if (tid == 0) s_b = (int)rois[(size_t)n * 5 + 0];
    if (tid < PP) {
        const float rx1 = rois[(size_t)n * 5 + 1];
        const float ry1 = rois[(size_t)n * 5 + 2];
        const float rx2 = rois[(size_t)n * 5 + 3];
        const float ry2 = rois[(size_t)n * 5 + 4];
        const float bw = (rx2 - rx1) / 7.0f;
        const float bh = (ry2 - ry1) / 7.0f;
        const int pi = tid / 7;
        const int pj = tid - pi * 7;
        float px = __fadd_rn(rx1, __fmul_rn((float)pj + 0.5f, bw));
        float py = __fadd_rn(ry1, __fmul_rn((float)pi + 0.5f, bh));
        px = fminf(fmaxf(px, 0.0f), (float)(IMW - 1));
        py = fminf(fmaxf(py, 0.0f), (float)(IMH - 1));
        const float fx = floorf(px), fy = floorf(py);
        const int x0 = (int)fx, y0 = (int)fy;
        s_x0[tid] = x0;
        s_y0[tid] = y0;
        s_x1[tid] = min(x0 + 1, IMW - 1);
        s_y1[tid] = min(y0 + 1, IMH - 1);
        s_wx[tid] = px - fx;
        s_wy[tid] = py - fy;
    }
    __syncthreads();

    const float* xb = x + (size_t)s_b * (CCH * IMH * IMW);
    _Float16*    crow = crops + (size_t)n * FANIN;

    for (int g = tid; g < FANIN / 2; g += 256) {
        const int i0 = g * 2;
        const int c0 = i0 / PP;
        const int p0 = i0 - c0 * PP;
        int c1 = c0, p1 = p0 + 1;
        if (p1 == PP) { p1 = 0; ++c1; }

        float v[2];
        const int cc[2] = {c0, c1};
        const int pp[2] = {p0, p1};
#pragma unroll
        for (int e = 0; e < 2; ++e) {
            const float* xc = xb + (size_t)cc[e] * (IMH * IMW);
            const int p = pp[e];
            const int x0 = s_x0[p], x1 = s_x1[p], y0 = s_y0[p], y1 = s_y1[p];
            const float wx = s_wx[p], wy = s_wy[p];
            const float v00 = xc[y0 * IMW + x0];
            const float v01 = xc[y0 * IMW + x1];
            const float v10 = xc[y1 * IMW + x0];
            const float v11 = xc[y1 * IMW + x1];
            const float top = v00 + wx * (v01 - v00);
            const float bot = v10 + wx * (v11 - v10);
            v[e] = top + wy * (bot - top);
        }
        f16x2 o = {(_Float16)v[0], (_Float16)v[1]};
        *(f16x2*)(crow + i0) = o;
    }
}

// ---------------------------------------------------------------------------
// f32 -> f16 weight conversion, vectorized (4 elems/thread).
// ---------------------------------------------------------------------------
__global__ __launch_bounds__(256) void convert_f16(
    const float* __restrict__ w, _Float16* __restrict__ wF, int n4)
{
    for (int g = blockIdx.x * 256 + threadIdx.x; g < n4; g += gridDim.x * 256) {
        const float4 v = ((const float4*)w)[g];
        f16x4 o = {(_Float16)v.x, (_Float16)v.y, (_Float16)v.z, (_Float16)v.w};
        ((f16x4*)wF)[g] = o;
    }
}

// ---------------------------------------------------------------------------
// f16 MFMA GEMM (NT): P[z] = A[M,K] * B[N,K]^T over K-slice z.
// 128x128 tile, BK=32, 4 waves of 64x64, swizzled LDS (2-way max).
// blockIdx.x = n-block (8 values) -> flat%8 pins weight strips per XCD.
// ---------------------------------------------------------------------------
__global__ __launch_bounds__(256, 4) void gemm_f16(
    const _Float16* __restrict__ A, const _Float16* __restrict__ B,
    float* __restrict__ P, int M, int N, int K, int kLen)
{
    __shared__ _Float16 lds[2][128][32];   // A, B tiles (8 KB each)

    const int tid  = threadIdx.x;
    const int wave = tid >> 6;
    const int lane = tid & 63;
    const int bm = blockIdx.y * 128;
    const int bn = blockIdx.x * 128;
    const int kBase = blockIdx.z * kLen;
    const int wr = wave >> 1, wc = wave & 1;

    f32x4 acc[4][4];
#pragma unroll
    for (int i = 0; i < 4; ++i)
#pragma unroll
        for (int j = 0; j < 4; ++j) acc[i][j] = (f32x4){0.f, 0.f, 0.f, 0.f};

    // ---- staging addressing (pre-swizzled global source) ----
    const int r_st = wave * 32 + (lane >> 2);                 // tile row, chunk 0
    const int s_st = ((lane & 3) ^ ((lane >> 3) & 3)) * 8;    // swizzled k-elem offset
    const _Float16* gA = A + (size_t)(bm + r_st) * K + kBase + s_st;
    const _Float16* gB = B + (size_t)(bn + r_st) * K + kBase + s_st;
    const size_t rstep = (size_t)16 * K;                      // +16 rows
    _Float16* lA = &lds[0][wave * 32][0];
    _Float16* lB = &lds[1][wave * 32][0];

    // ---- fragment read addressing ----
    const int li = lane & 15;
    const int sw = (((li >> 1) & 3) ^ (lane >> 4)) * 8;       // swizzled slot

    for (int kt = 0; kt < kLen; kt += 32) {
        gload16(gA + kt, lA);  gload16(gA + kt + rstep, lA + 16 * 32);
        gload16(gB + kt, lB);  gload16(gB + kt + rstep, lB + 16 * 32);
        __syncthreads();

        f16x8 a[4], b[4];
#pragma unroll
        for (int m = 0; m < 4; ++m)
            a[m] = *(const f16x8*)&lds[0][wr * 64 + m * 16 + li][sw];
#pragma unroll
        for (int n = 0; n < 4; ++n)
            b[n] = *(const f16x8*)&lds[1][wc * 64 + n * 16 + li][sw];
#pragma unroll
        for (int m = 0; m < 4; ++m)
#pragma unroll
            for (int n = 0; n < 4; ++n)
                acc[m][n] = __builtin_amdgcn_mfma_f32_16x16x32_f16(a[m], b[n], acc[m][n], 0, 0, 0);
        __syncthreads();
    }

    float* Pz = P + (size_t)blockIdx.z * M * N;
#pragma unroll
    for (int m = 0; m < 4; ++m)
#pragma unroll
        for (int n = 0; n < 4; ++n) {
            const int col = bn + wc * 64 + n * 16 + li;
#pragma unroll
            for (int e = 0; e < 4; ++e) {
                const int row = bm + wr * 64 + m * 16 + (lane >> 4) * 4 + e;
                Pz[(size_t)row * N + col] = acc[m][n][e];
            }
        }
}

// ---------------------------------------------------------------------------
// relu(sum_z P[z] + bias) -> f16
// ---------------------------------------------------------------------------
__global__ __launch_bounds__(256) void combine_relu_f16(
    const float* __restrict__ P, int Z, const float* __restrict__ bias,
    _Float16* __restrict__ H)
{
    const int g = blockIdx.x * 256 + threadIdx.x;
    const size_t MN4 = (size_t)NROI * HID / 4;
    float4 s = ((const float4*)P)[g];
    for (int z = 1; z < Z; ++z) {
        const float4 p = ((const float4*)P)[z * MN4 + g];
        s.x += p.x; s.y += p.y; s.z += p.z; s.w += p.w;
    }
    const float4 bv = *(const float4*)(bias + (g & 255) * 4);
    f16x4 o = {(_Float16)fmaxf(s.x + bv.x, 0.0f),
               (_Float16)fmaxf(s.y + bv.y, 0.0f),
               (_Float16)fmaxf(s.z + bv.z, 0.0f),
               (_Float16)fmaxf(s.w + bv.w, 0.0f)};
    ((f16x4*)H)[g] = o;
}

// ---------------------------------------------------------------------------
// relu(sum_z P[z] + bias) -> f32 (writes onto P[0] elementwise - safe alias)
// ---------------------------------------------------------------------------
__global__ __launch_bounds__(256) void combine_relu_f32(
    const float* __restrict__ P, int Z, const float* __restrict__ bias,
    float* __restrict__ H)
{
    const int g = blockIdx.x * 256 + threadIdx.x;
    const size_t MN4 = (size_t)NROI * HID / 4;
    float4 s = ((const float4*)P)[g];
    for (int z = 1; z < Z; ++z) {
        const float4 p = ((const float4*)P)[z * MN4 + g];
        s.x += p.x; s.y += p.y; s.z += p.z; s.w += p.w;
    }
    const float4 bv = *(const float4*)(bias + (g & 255) * 4);
    float4 r;
    r.x = fmaxf(s.x + bv.x, 0.0f);
    r.y = fmaxf(s.y + bv.y, 0.0f);
    r.z = fmaxf(s.z + bv.z, 0.0f);
    r.w = fmaxf(s.w + bv.w, 0.0f);
    ((float4*)H)[g] = r;
}

// ---------------------------------------------------------------------------
// heads: one wave per ROI row; 10 dots of K=1024, shfl_xor reduce.
// ---------------------------------------------------------------------------
__global__ __launch_bounds__(256) void heads_kernel(
    const float* __restrict__ h2,
    const float* __restrict__ wc, const float* __restrict__ bc,
    const float* __restrict__ wb, const float* __restrict__ bb,
    float* __restrict__ out)
{
    const int gw   = (blockIdx.x * 256 + threadIdx.x) >> 6;   // 0..2047
    const int lane = threadIdx.x & 63;
    const float* hrow = h2 + (size_t)gw * HID;

    float4 h[4];
#pragma unroll
    for (int j = 0; j < 4; ++j)
        h[j] = *(const float4*)(hrow + lane * 16 + j * 4);

    float keep = 0.0f;
#pragma unroll
    for (int o = 0; o < 10; ++o) {
        const float* wrow = (o < 2) ? (wc + (size_t)o * HID)
                                    : (wb + (size_t)(o - 2) * HID);
        float acc = 0.0f;
#pragma unroll
        for (int j = 0; j < 4; ++j) {
            const float4 w4 = *(const float4*)(wrow + lane * 16 + j * 4);
            acc += h[j].x * w4.x + h[j].y * w4.y + h[j].z * w4.z + h[j].w * w4.w;
        }
#pragma unroll
        for (int s = 32; s; s >>= 1) acc += __shfl_xor(acc, s, 64);
        if (lane == o) keep = acc;
    }
    if (lane < 2)        out[gw * 2 + lane] = keep + bc[lane];
    else if (lane < 10)  out[NROI * 2 + gw * 8 + (lane - 2)] = keep + bb[lane - 2];
}

// ---------------------------------------------------------------------------
extern "C" void kernel_launch(void* const* d_in, const int* in_sizes, int n_in,
                              void* d_out, int out_size, void* d_ws, size_t ws_size,
                              hipStream_t stream)
{
    const float* x    = (const float*)d_in[0];
    const float* rois = (const float*)d_in[1];
    const float* w1   = (const float*)d_in[2];
    const float* b1   = (const float*)d_in[3];
    const float* w2   = (const float*)d_in[4];
    const float* b2   = (const float*)d_in[5];
    const float* wc   = (const float*)d_in[6];
    const float* bc   = (const float*)d_in[7];
    const float* wb   = (const float*)d_in[8];
    const float* bb   = (const float*)d_in[9];
    float* out = (float*)d_out;

    char* ws = (char*)d_ws;
    const size_t CRB = (size_t)NROI * FANIN * 2;     // 51,380,224
    const size_t W1B = (size_t)HID * FANIN * 2;      // 25,690,112
    const size_t W2B = (size_t)HID * HID * 2;        //  2,097,152
    const size_t PB  = (size_t)NROI * HID * 4;       //  8,388,608 per z-slice
    const size_t HB  = (size_t)NROI * HID * 2;       //  4,194,304

    const int Z1 = 8;   // FC1 K-split: 12544/8 = 1568 (49 K-steps)
    const int Z2 = 4;   // FC2 K-split: 1024/4  = 256  (8 K-steps)

    _Float16* cropsF = (_Float16*)(ws);
    _Float16* w1F    = (_Float16*)(ws + CRB);
    _Float16* w2F    = (_Float16*)(ws + CRB + W1B);
    float*    P      = (float*)(ws + CRB + W1B + W2B);
    _Float16* h1F    = (_Float16*)(ws + CRB + W1B + W2B + (size_t)Z1 * PB);
    float*    h2     = P;   // elementwise alias with P[0] in combine_relu_f32

    // weight conversions
    convert_f16<<<2048, 256, 0, stream>>>(w1, w1F, HID * FANIN / 4);
    convert_f16<<<1024, 256, 0, stream>>>(w2, w2F, HID * HID / 4);

    // RoIAlign -> f16 crops
    roi_align_kernel<<<NROI, 256, 0, stream>>>(x, rois, cropsF);

    // FC1: K = 12544
    gemm_f16<<<dim3(HID / 128, NROI / 128, Z1), 256, 0, stream>>>(
        cropsF, w1F, P, NROI, HID, FANIN, FANIN / Z1);
    combine_relu_f16<<<(NROI * HID / 4) / 256, 256, 0, stream>>>(P, Z1, b1, h1F);

    // FC2: K = 1024
    gemm_f16<<<dim3(HID / 128, NROI / 128, Z2), 256, 0, stream>>>(
        h1F, w2F, P, NROI, HID, HID, HID / Z2);
    combine_relu_f32<<<(NROI * HID / 4) / 256, 256, 0, stream>>>(P, Z2, b2, h2);

    // heads
    heads_kernel<<<NROI / 4, 256, 0, stream>>>(h2, wc, bc, wb, bb, out);
}

// Round 5
// 256.509 us; speedup vs baseline: 4.0019x; 1.2442x over previous
//
#include <hip/hip_runtime.h>

#define NROI  2048
#define CCH   256
#define IMH   200
#define IMW   200
#define CROP  7
#define PP    49
#define FANIN 12544
#define HID   1024
#define SL    204     // LDS slab row stride (f16), 8B-aligned rows, bank-spread

typedef _Float16 f16x8 __attribute__((ext_vector_type(8)));
typedef _Float16 f16x4 __attribute__((ext_vector_type(4)));
typedef __attribute__((ext_vector_type(4))) float f32x4;

__device__ __forceinline__ void gload16(const void* g, void* l) {
    __builtin_amdgcn_global_load_lds(
        (const __attribute__((address_space(1))) void*)g,
        (__attribute__((address_space(3))) void*)l, 16, 0, 0);
}

// ---------------------------------------------------------------------------
// zero the 4 per-image ROI counters (ws not re-poisoned between replays)
// ---------------------------------------------------------------------------
__global__ void zero_cnt_kernel(int* __restrict__ cnt) {
    if (threadIdx.x < 4) cnt[threadIdx.x] = 0;
}

// ---------------------------------------------------------------------------
// Per-ROI geometry: 7 column entries {x0,x1,wx}, 7 row entries {y0,y1,wy},
// plus per-image ROI lists (atomic append; output is order-independent).
// ---------------------------------------------------------------------------
__global__ __launch_bounds__(256) void roi_geom_kernel(
    const float* __restrict__ rois,
    uint2* __restrict__ geomX, uint2* __restrict__ geomY,
    int* __restrict__ list, int* __restrict__ cnt)
{
    const int n = blockIdx.x * 256 + threadIdx.x;
    if (n >= NROI) return;
    const float bi  = rois[(size_t)n * 5 + 0];
    const float rx1 = rois[(size_t)n * 5 + 1];
    const float ry1 = rois[(size_t)n * 5 + 2];
    const float rx2 = rois[(size_t)n * 5 + 3];
    const float ry2 = rois[(size_t)n * 5 + 4];
    const float bw = (rx2 - rx1) / 7.0f;
    const float bh = (ry2 - ry1) / 7.0f;
#pragma unroll
    for (int j = 0; j < 7; ++j) {
        float px = __fadd_rn(rx1, __fmul_rn((float)j + 0.5f, bw));
        px = fminf(fmaxf(px, 0.0f), (float)(IMW - 1));
        const float fx = floorf(px);
        const int x0 = (int)fx;
        const int x1 = min(x0 + 1, IMW - 1);
        geomX[n * 7 + j] = make_uint2((unsigned)x0 | ((unsigned)x1 << 16),
                                      __float_as_uint(px - fx));
        float py = __fadd_rn(ry1, __fmul_rn((float)j + 0.5f, bh));
        py = fminf(fmaxf(py, 0.0f), (float)(IMH - 1));
        const float fy = floorf(py);
        const int y0 = (int)fy;
        const int y1 = min(y0 + 1, IMH - 1);
        geomY[n * 7 + j] = make_uint2((unsigned)y0 | ((unsigned)y1 << 16),
                                      __float_as_uint(py - fy));
    }
    const int b = (int)bi;
    const int slot = atomicAdd(&cnt[b], 1);
    list[b * NROI + slot] = n;
}

// ---------------------------------------------------------------------------
// RoIAlign, slab-resident: block = (channel c, image b). Stage x[b][c]
// (200x200 f32 -> f16 LDS, coalesced, read-once), then 16 waves sweep the
// image's ROIs; lane p<49 does 4 LDS reads + bilinear, 98B contiguous store.
// ---------------------------------------------------------------------------
__global__ __launch_bounds__(1024) void roi_align_kernel(
    const float* __restrict__ x,
    const uint2* __restrict__ geomX, const uint2* __restrict__ geomY,
    const int* __restrict__ list, const int* __restrict__ cnt,
    _Float16* __restrict__ crops)
{
    __shared__ _Float16 slab[IMH * SL];   // 81,600 B

    const int c = blockIdx.x;
    const int b = blockIdx.y;
    const int tid  = threadIdx.x;
    const int wave = tid >> 6;
    const int lane = tid & 63;

    // ---- stage slab: 40,000 floats = 10,000 float4 ----
    const float* src = x + ((size_t)b * CCH + c) * (IMH * IMW);
    for (int g = tid; g < (IMH * IMW / 4); g += 1024) {
        const int row  = g / (IMW / 4);
        const int col4 = (g - row * (IMW / 4)) * 4;
        const float4 v = *(const float4*)(src + row * IMW + col4);
        f16x4 o = {(_Float16)v.x, (_Float16)v.y, (_Float16)v.z, (_Float16)v.w};
        *(f16x4*)&slab[row * SL + col4] = o;
    }
    __syncthreads();

    const int nb = cnt[b];
    const int i = lane / 7;               // bin row  (y)
    const int j = lane - i * 7;           // bin col  (x)
    const bool active = lane < PP;

    for (int idx = wave; idx < nb; idx += 16) {
        const int n = list[b * NROI + idx];
        if (active) {
            const uint2 gx = geomX[n * 7 + j];
            const uint2 gy = geomY[n * 7 + i];
            const int x0 = gx.x & 0xFFFF, x1 = gx.x >> 16;
            const int y0 = gy.x & 0xFFFF, y1 = gy.x >> 16;
            const float wx = __uint_as_float(gx.y);
            const float wy = __uint_as_float(gy.y);
            const float v00 = (float)slab[y0 * SL + x0];
            const float v01 = (float)slab[y0 * SL + x1];
            const float v10 = (float)slab[y1 * SL + x0];
            const float v11 = (float)slab[y1 * SL + x1];
            const float top = v00 + wx * (v01 - v00);
            const float bot = v10 + wx * (v11 - v10);
            const float val = top + wy * (bot - top);
            crops[(size_t)n * FANIN + c * PP + lane] = (_Float16)val;
        }
    }
}

// ---------------------------------------------------------------------------
// f32 -> f16 weight conversion, vectorized (4 elems/thread).
// ---------------------------------------------------------------------------
__global__ __launch_bounds__(256) void convert_f16(
    const float* __restrict__ w, _Float16* __restrict__ wF, int n4)
{
    for (int g = blockIdx.x * 256 + threadIdx.x; g < n4; g += gridDim.x * 256) {
        const float4 v = ((const float4*)w)[g];
        f16x4 o = {(_Float16)v.x, (_Float16)v.y, (_Float16)v.z, (_Float16)v.w};
        ((f16x4*)wF)[g] = o;
    }
}

// ---------------------------------------------------------------------------
// f16 MFMA GEMM (NT): P[z] = A[M,K] * B[N,K]^T over K-slice z.
// 128x128 tile, BK=32, 4 waves of 64x64, swizzled LDS (2-way max).
// ---------------------------------------------------------------------------
__global__ __launch_bounds__(256, 4) void gemm_f16(
    const _Float16* __restrict__ A, const _Float16* __restrict__ B,
    float* __restrict__ P, int M, int N, int K, int kLen)
{
    __shared__ _Float16 lds[2][128][32];   // A, B tiles (8 KB each)

    const int tid  = threadIdx.x;
    const int wave = tid >> 6;
    const int lane = tid & 63;
    const int bm = blockIdx.y * 128;
    const int bn = blockIdx.x * 128;
    const int kBase = blockIdx.z * kLen;
    const int wr = wave >> 1, wc = wave & 1;

    f32x4 acc[4][4];
#pragma unroll
    for (int i = 0; i < 4; ++i)
#pragma unroll
        for (int j = 0; j < 4; ++j) acc[i][j] = (f32x4){0.f, 0.f, 0.f, 0.f};

    const int r_st = wave * 32 + (lane >> 2);
    const int s_st = ((lane & 3) ^ ((lane >> 3) & 3)) * 8;
    const _Float16* gA = A + (size_t)(bm + r_st) * K + kBase + s_st;
    const _Float16* gB = B + (size_t)(bn + r_st) * K + kBase + s_st;
    const size_t rstep = (size_t)16 * K;
    _Float16* lA = &lds[0][wave * 32][0];
    _Float16* lB = &lds[1][wave * 32][0];

    const int li = lane & 15;
    const int sw = (((li >> 1) & 3) ^ (lane >> 4)) * 8;

    for (int kt = 0; kt < kLen; kt += 32) {
        gload16(gA + kt, lA);  gload16(gA + kt + rstep, lA + 16 * 32);
        gload16(gB + kt, lB);  gload16(gB + kt + rstep, lB + 16 * 32);
        __syncthreads();

        f16x8 a[4], b[4];
#pragma unroll
        for (int m = 0; m < 4; ++m)
            a[m] = *(const f16x8*)&lds[0][wr * 64 + m * 16 + li][sw];
#pragma unroll
        for (int n = 0; n < 4; ++n)
            b[n] = *(const f16x8*)&lds[1][wc * 64 + n * 16 + li][sw];
#pragma unroll
        for (int m = 0; m < 4; ++m)
#pragma unroll
            for (int n = 0; n < 4; ++n)
                acc[m][n] = __builtin_amdgcn_mfma_f32_16x16x32_f16(a[m], b[n], acc[m][n], 0, 0, 0);
        __syncthreads();
    }

    float* Pz = P + (size_t)blockIdx.z * M * N;
#pragma unroll
    for (int m = 0; m < 4; ++m)
#pragma unroll
        for (int n = 0; n < 4; ++n) {
            const int col = bn + wc * 64 + n * 16 + li;
#pragma unroll
            for (int e = 0; e < 4; ++e) {
                const int row = bm + wr * 64 + m * 16 + (lane >> 4) * 4 + e;
                Pz[(size_t)row * N + col] = acc[m][n][e];
            }
        }
}

// ---------------------------------------------------------------------------
// relu(sum_z P[z] + bias) -> f16
// ---------------------------------------------------------------------------
__global__ __launch_bounds__(256) void combine_relu_f16(
    const float* __restrict__ P, int Z, const float* __restrict__ bias,
    _Float16* __restrict__ H)
{
    const int g = blockIdx.x * 256 + threadIdx.x;
    const size_t MN4 = (size_t)NROI * HID / 4;
    float4 s = ((const float4*)P)[g];
    for (int z = 1; z < Z; ++z) {
        const float4 p = ((const float4*)P)[z * MN4 + g];
        s.x += p.x; s.y += p.y; s.z += p.z; s.w += p.w;
    }
    const float4 bv = *(const float4*)(bias + (g & 255) * 4);
    f16x4 o = {(_Float16)fmaxf(s.x + bv.x, 0.0f),
               (_Float16)fmaxf(s.y + bv.y, 0.0f),
               (_Float16)fmaxf(s.z + bv.z, 0.0f),
               (_Float16)fmaxf(s.w + bv.w, 0.0f)};
    ((f16x4*)H)[g] = o;
}

// ---------------------------------------------------------------------------
// relu(sum_z P[z] + bias) -> f32 (aliases P[0] elementwise - safe)
// ---------------------------------------------------------------------------
__global__ __launch_bounds__(256) void combine_relu_f32(
    const float* __restrict__ P, int Z, const float* __restrict__ bias,
    float* __restrict__ H)
{
    const int g = blockIdx.x * 256 + threadIdx.x;
    const size_t MN4 = (size_t)NROI * HID / 4;
    float4 s = ((const float4*)P)[g];
    for (int z = 1; z < Z; ++z) {
        const float4 p = ((const float4*)P)[z * MN4 + g];
        s.x += p.x; s.y += p.y; s.z += p.z; s.w += p.w;
    }
    const float4 bv = *(const float4*)(bias + (g & 255) * 4);
    float4 r;
    r.x = fmaxf(s.x + bv.x, 0.0f);
    r.y = fmaxf(s.y + bv.y, 0.0f);
    r.z = fmaxf(s.z + bv.z, 0.0f);
    r.w = fmaxf(s.w + bv.w, 0.0f);
    ((float4*)H)[g] = r;
}

// ---------------------------------------------------------------------------
// heads: one wave per ROI row; 10 dots of K=1024, shfl_xor reduce.
// ---------------------------------------------------------------------------
__global__ __launch_bounds__(256) void heads_kernel(
    const float* __restrict__ h2,
    const float* __restrict__ wc, const float* __restrict__ bc,
    const float* __restrict__ wb, const float* __restrict__ bb,
    float* __restrict__ out)
{
    const int gw   = (blockIdx.x * 256 + threadIdx.x) >> 6;
    const int lane = threadIdx.x & 63;
    const float* hrow = h2 + (size_t)gw * HID;

    float4 h[4];
#pragma unroll
    for (int j = 0; j < 4; ++j)
        h[j] = *(const float4*)(hrow + lane * 16 + j * 4);

    float keep = 0.0f;
#pragma unroll
    for (int o = 0; o < 10; ++o) {
        const float* wrow = (o < 2) ? (wc + (size_t)o * HID)
                                    : (wb + (size_t)(o - 2) * HID);
        float acc = 0.0f;
#pragma unroll
        for (int j = 0; j < 4; ++j) {
            const float4 w4 = *(const float4*)(wrow + lane * 16 + j * 4);
            acc += h[j].x * w4.x + h[j].y * w4.y + h[j].z * w4.z + h[j].w * w4.w;
        }
#pragma unroll
        for (int s = 32; s; s >>= 1) acc += __shfl_xor(acc, s, 64);
        if (lane == o) keep = acc;
    }
    if (lane < 2)        out[gw * 2 + lane] = keep + bc[lane];
    else if (lane < 10)  out[NROI * 2 + gw * 8 + (lane - 2)] = keep + bb[lane - 2];
}

// ---------------------------------------------------------------------------
extern "C" void kernel_launch(void* const* d_in, const int* in_sizes, int n_in,
                              void* d_out, int out_size, void* d_ws, size_t ws_size,
                              hipStream_t stream)
{
    const float* x    = (const float*)d_in[0];
    const float* rois = (const float*)d_in[1];
    const float* w1   = (const float*)d_in[2];
    const float* b1   = (const float*)d_in[3];
    const float* w2   = (const float*)d_in[4];
    const float* b2   = (const float*)d_in[5];
    const float* wc   = (const float*)d_in[6];
    const float* bc   = (const float*)d_in[7];
    const float* wb   = (const float*)d_in[8];
    const float* bb   = (const float*)d_in[9];
    float* out = (float*)d_out;

    char* ws = (char*)d_ws;
    const size_t CRB = (size_t)NROI * FANIN * 2;     // 51,380,224
    const size_t W1B = (size_t)HID * FANIN * 2;      // 25,690,112
    const size_t W2B = (size_t)HID * HID * 2;        //  2,097,152
    const size_t PB  = (size_t)NROI * HID * 4;       //  8,388,608 per z-slice
    const size_t HB  = (size_t)NROI * HID * 2;       //  4,194,304
    const size_t GXB = (size_t)NROI * 7 * 8;         //    114,688
    const size_t LSB = (size_t)4 * NROI * 4;         //     32,768

    const int Z1 = 8;   // FC1 K-split: 12544/8 = 1568 (49 K-steps)
    const int Z2 = 4;   // FC2 K-split: 1024/4  = 256  (8 K-steps)

    size_t off = 0;
    _Float16* cropsF = (_Float16*)(ws + off); off += CRB;
    _Float16* w1F    = (_Float16*)(ws + off); off += W1B;
    _Float16* w2F    = (_Float16*)(ws + off); off += W2B;
    float*    P      = (float*)(ws + off);    off += (size_t)Z1 * PB;
    _Float16* h1F    = (_Float16*)(ws + off); off += HB;
    uint2*    geomX  = (uint2*)(ws + off);    off += GXB;
    uint2*    geomY  = (uint2*)(ws + off);    off += GXB;
    int*      list   = (int*)(ws + off);      off += LSB;
    int*      cnt    = (int*)(ws + off);      off += 64;
    float*    h2     = P;   // elementwise alias with P[0] in combine_relu_f32

    // ROI geometry + per-image lists
    zero_cnt_kernel<<<1, 64, 0, stream>>>(cnt);
    roi_geom_kernel<<<NROI / 256, 256, 0, stream>>>(rois, geomX, geomY, list, cnt);

    // weight conversions
    convert_f16<<<2048, 256, 0, stream>>>(w1, w1F, HID * FANIN / 4);
    convert_f16<<<1024, 256, 0, stream>>>(w2, w2F, HID * HID / 4);

    // RoIAlign: block per (channel, image), slab in LDS
    roi_align_kernel<<<dim3(CCH, 4), 1024, 0, stream>>>(
        x, geomX, geomY, list, cnt, cropsF);

    // FC1: K = 12544
    gemm_f16<<<dim3(HID / 128, NROI / 128, Z1), 256, 0, stream>>>(
        cropsF, w1F, P, NROI, HID, FANIN, FANIN / Z1);
    combine_relu_f16<<<(NROI * HID / 4) / 256, 256, 0, stream>>>(P, Z1, b1, h1F);

    // FC2: K = 1024
    gemm_f16<<<dim3(HID / 128, NROI / 128, Z2), 256, 0, stream>>>(
        h1F, w2F, P, NROI, HID, HID, HID / Z2);
    combine_relu_f32<<<(NROI * HID / 4) / 256, 256, 0, stream>>>(P, Z2, b2, h2);

    // heads
    heads_kernel<<<NROI / 4, 256, 0, stream>>>(h2, wc, bc, wb, bb, out);
}

// Round 6
// 248.131 us; speedup vs baseline: 4.1371x; 1.0338x over previous
//
#include <hip/hip_runtime.h>

#define NROI  2048
#define CCH   256
#define IMH   200
#define IMW   200
#define CROP  7
#define PP    49
#define FANIN 12544
#define HID   1024

typedef _Float16 f16x8 __attribute__((ext_vector_type(8)));
typedef _Float16 f16x4 __attribute__((ext_vector_type(4)));
typedef __attribute__((ext_vector_type(4))) float f32x4;

__device__ __forceinline__ void gload16(const void* g, void* l) {
    __builtin_amdgcn_global_load_lds(
        (const __attribute__((address_space(1))) void*)g,
        (__attribute__((address_space(3))) void*)l, 16, 0, 0);
}

// ---------------------------------------------------------------------------
// zero the 4 per-image ROI counters (ws not re-poisoned between replays)
// ---------------------------------------------------------------------------
__global__ void zero_cnt_kernel(int* __restrict__ cnt) {
    if (threadIdx.x < 4) cnt[threadIdx.x] = 0;
}

// ---------------------------------------------------------------------------
// Per-ROI geometry: 7 column entries {x0,x1,wx}, 7 row entries {y0,y1,wy},
// plus per-image ROI lists (atomic append; output is order-independent).
// ---------------------------------------------------------------------------
__global__ __launch_bounds__(256) void roi_geom_kernel(
    const float* __restrict__ rois,
    uint2* __restrict__ geomX, uint2* __restrict__ geomY,
    int* __restrict__ list, int* __restrict__ cnt)
{
    const int n = blockIdx.x * 256 + threadIdx.x;
    if (n >= NROI) return;
    const float bi  = rois[(size_t)n * 5 + 0];
    const float rx1 = rois[(size_t)n * 5 + 1];
    const float ry1 = rois[(size_t)n * 5 + 2];
    const float rx2 = rois[(size_t)n * 5 + 3];
    const float ry2 = rois[(size_t)n * 5 + 4];
    const float bw = (rx2 - rx1) / 7.0f;
    const float bh = (ry2 - ry1) / 7.0f;
#pragma unroll
    for (int j = 0; j < 7; ++j) {
        float px = __fadd_rn(rx1, __fmul_rn((float)j + 0.5f, bw));
        px = fminf(fmaxf(px, 0.0f), (float)(IMW - 1));
        const float fx = floorf(px);
        const int x0 = (int)fx;
        const int x1 = min(x0 + 1, IMW - 1);
        geomX[n * 7 + j] = make_uint2((unsigned)x0 | ((unsigned)x1 << 16),
                                      __float_as_uint(px - fx));
        float py = __fadd_rn(ry1, __fmul_rn((float)j + 0.5f, bh));
        py = fminf(fmaxf(py, 0.0f), (float)(IMH - 1));
        const float fy = floorf(py);
        const int y0 = (int)fy;
        const int y1 = min(y0 + 1, IMH - 1);
        geomY[n * 7 + j] = make_uint2((unsigned)y0 | ((unsigned)y1 << 16),
                                      __float_as_uint(py - fy));
    }
    const int b = (int)bi;
    const int slot = atomicAdd(&cnt[b], 1);
    list[b * NROI + slot] = n;
}

// ---------------------------------------------------------------------------
// RoIAlign, slab-resident: block = (channel c, image b). Stage x[b][c]
// (200x200 f32 -> f16 LDS, linear copy), then 16 waves sweep the image's
// ROIs with a depth-2 software pipeline (prefetch n+geometry of iter k+1
// while iter k's LDS reads / store retire).
// ---------------------------------------------------------------------------
__global__ __launch_bounds__(1024) void roi_align_kernel(
    const float* __restrict__ x,
    const uint2* __restrict__ geomX, const uint2* __restrict__ geomY,
    const int* __restrict__ list, const int* __restrict__ cnt,
    _Float16* __restrict__ crops)
{
    __shared__ _Float16 slab[IMH * IMW];   // 80,000 B -> 2 blocks/CU

    const int c = blockIdx.x;
    const int b = blockIdx.y;
    const int tid  = threadIdx.x;
    const int wave = tid >> 6;
    const int lane = tid & 63;

    // ---- stage slab: linear 10,000 x float4 -> f16x4 ----
    const float* src = x + ((size_t)b * CCH + c) * (IMH * IMW);
    for (int g = tid; g < (IMH * IMW / 4); g += 1024) {
        const float4 v = ((const float4*)src)[g];
        f16x4 o = {(_Float16)v.x, (_Float16)v.y, (_Float16)v.z, (_Float16)v.w};
        *(f16x4*)&slab[g * 4] = o;
    }
    __syncthreads();

    const int nb = cnt[b];
    const int base = b * NROI;
    const bool active = lane < PP;
    const int i = active ? lane / 7 : 0;       // bin row (y)
    const int j = active ? lane - i * 7 : 0;   // bin col (x)
    _Float16* cdst = crops + (size_t)c * PP + lane;

    int idx = wave;
    int   nA = 0;
    uint2 gxA = make_uint2(0, 0), gyA = make_uint2(0, 0);
    if (idx < nb) {
        nA  = list[base + idx];
        gxA = geomX[nA * 7 + j];
        gyA = geomY[nA * 7 + i];
    }
    while (idx < nb) {
        const int idxN = idx + 16;
        int   nB = 0;
        uint2 gxB = make_uint2(0, 0), gyB = make_uint2(0, 0);
        if (idxN < nb) {
            nB  = list[base + idxN];
            gxB = geomX[nB * 7 + j];
            gyB = geomY[nB * 7 + i];
        }
        // ---- compute + store iteration A ----
        {
            const int x0 = gxA.x & 0xFFFF, x1 = gxA.x >> 16;
            const int y0 = gyA.x & 0xFFFF, y1 = gyA.x >> 16;
            const float wx = __uint_as_float(gxA.y);
            const float wy = __uint_as_float(gyA.y);
            const float v00 = (float)slab[y0 * IMW + x0];
            const float v01 = (float)slab[y0 * IMW + x1];
            const float v10 = (float)slab[y1 * IMW + x0];
            const float v11 = (float)slab[y1 * IMW + x1];
            const float top = v00 + wx * (v01 - v00);
            const float bot = v10 + wx * (v11 - v10);
            const float val = top + wy * (bot - top);
            if (active) cdst[(size_t)nA * FANIN] = (_Float16)val;
        }
        idx = idxN; nA = nB; gxA = gxB; gyA = gyB;
    }
}

// ---------------------------------------------------------------------------
// f32 -> f16 weight conversion, vectorized (4 elems/thread).
// ---------------------------------------------------------------------------
__global__ __launch_bounds__(256) void convert_f16(
    const float* __restrict__ w, _Float16* __restrict__ wF, int n4)
{
    for (int g = blockIdx.x * 256 + threadIdx.x; g < n4; g += gridDim.x * 256) {
        const float4 v = ((const float4*)w)[g];
        f16x4 o = {(_Float16)v.x, (_Float16)v.y, (_Float16)v.z, (_Float16)v.w};
        ((f16x4*)wF)[g] = o;
    }
}

// ---------------------------------------------------------------------------
// f16 MFMA GEMM (NT): P[z] = A[M,K] * B[N,K]^T over K-slice z.
// 128x128 tile, BK=32, 4 waves of 64x64, swizzled LDS (2-way max).
// ---------------------------------------------------------------------------
__global__ __launch_bounds__(256, 4) void gemm_f16(
    const _Float16* __restrict__ A, const _Float16* __restrict__ B,
    float* __restrict__ P, int M, int N, int K, int kLen)
{
    __shared__ _Float16 lds[2][128][32];   // A, B tiles (8 KB each)

    const int tid  = threadIdx.x;
    const int wave = tid >> 6;
    const int lane = tid & 63;
    const int bm = blockIdx.y * 128;
    const int bn = blockIdx.x * 128;
    const int kBase = blockIdx.z * kLen;
    const int wr = wave >> 1, wc = wave & 1;

    f32x4 acc[4][4];
#pragma unroll
    for (int i = 0; i < 4; ++i)
#pragma unroll
        for (int j = 0; j < 4; ++j) acc[i][j] = (f32x4){0.f, 0.f, 0.f, 0.f};

    const int r_st = wave * 32 + (lane >> 2);
    const int s_st = ((lane & 3) ^ ((lane >> 3) & 3)) * 8;
    const _Float16* gA = A + (size_t)(bm + r_st) * K + kBase + s_st;
    const _Float16* gB = B + (size_t)(bn + r_st) * K + kBase + s_st;
    const size_t rstep = (size_t)16 * K;
    _Float16* lA = &lds[0][wave * 32][0];
    _Float16* lB = &lds[1][wave * 32][0];

    const int li = lane & 15;
    const int sw = (((li >> 1) & 3) ^ (lane >> 4)) * 8;

    for (int kt = 0; kt < kLen; kt += 32) {
        gload16(gA + kt, lA);  gload16(gA + kt + rstep, lA + 16 * 32);
        gload16(gB + kt, lB);  gload16(gB + kt + rstep, lB + 16 * 32);
        __syncthreads();

        f16x8 a[4], b[4];
#pragma unroll
        for (int m = 0; m < 4; ++m)
            a[m] = *(const f16x8*)&lds[0][wr * 64 + m * 16 + li][sw];
#pragma unroll
        for (int n = 0; n < 4; ++n)
            b[n] = *(const f16x8*)&lds[1][wc * 64 + n * 16 + li][sw];
#pragma unroll
        for (int m = 0; m < 4; ++m)
#pragma unroll
            for (int n = 0; n < 4; ++n)
                acc[m][n] = __builtin_amdgcn_mfma_f32_16x16x32_f16(a[m], b[n], acc[m][n], 0, 0, 0);
        __syncthreads();
    }

    float* Pz = P + (size_t)blockIdx.z * M * N;
#pragma unroll
    for (int m = 0; m < 4; ++m)
#pragma unroll
        for (int n = 0; n < 4; ++n) {
            const int col = bn + wc * 64 + n * 16 + li;
#pragma unroll
            for (int e = 0; e < 4; ++e) {
                const int row = bm + wr * 64 + m * 16 + (lane >> 4) * 4 + e;
                Pz[(size_t)row * N + col] = acc[m][n][e];
            }
        }
}

// ---------------------------------------------------------------------------
// relu(sum_z P[z] + bias) -> f16
// ---------------------------------------------------------------------------
__global__ __launch_bounds__(256) void combine_relu_f16(
    const float* __restrict__ P, int Z, const float* __restrict__ bias,
    _Float16* __restrict__ H)
{
    const int g = blockIdx.x * 256 + threadIdx.x;
    const size_t MN4 = (size_t)NROI * HID / 4;
    float4 s = ((const float4*)P)[g];
    for (int z = 1; z < Z; ++z) {
        const float4 p = ((const float4*)P)[z * MN4 + g];
        s.x += p.x; s.y += p.y; s.z += p.z; s.w += p.w;
    }
    const float4 bv = *(const float4*)(bias + (g & 255) * 4);
    f16x4 o = {(_Float16)fmaxf(s.x + bv.x, 0.0f),
               (_Float16)fmaxf(s.y + bv.y, 0.0f),
               (_Float16)fmaxf(s.z + bv.z, 0.0f),
               (_Float16)fmaxf(s.w + bv.w, 0.0f)};
    ((f16x4*)H)[g] = o;
}

// ---------------------------------------------------------------------------
// relu(sum_z P[z] + bias) -> f32 (aliases P[0] elementwise - safe)
// ---------------------------------------------------------------------------
__global__ __launch_bounds__(256) void combine_relu_f32(
    const float* __restrict__ P, int Z, const float* __restrict__ bias,
    float* __restrict__ H)
{
    const int g = blockIdx.x * 256 + threadIdx.x;
    const size_t MN4 = (size_t)NROI * HID / 4;
    float4 s = ((const float4*)P)[g];
    for (int z = 1; z < Z; ++z) {
        const float4 p = ((const float4*)P)[z * MN4 + g];
        s.x += p.x; s.y += p.y; s.z += p.z; s.w += p.w;
    }
    const float4 bv = *(const float4*)(bias + (g & 255) * 4);
    float4 r;
    r.x = fmaxf(s.x + bv.x, 0.0f);
    r.y = fmaxf(s.y + bv.y, 0.0f);
    r.z = fmaxf(s.z + bv.z, 0.0f);
    r.w = fmaxf(s.w + bv.w, 0.0f);
    ((float4*)H)[g] = r;
}

// ---------------------------------------------------------------------------
// heads: one wave per ROI row; 10 dots of K=1024, shfl_xor reduce.
// ---------------------------------------------------------------------------
__global__ __launch_bounds__(256) void heads_kernel(
    const float* __restrict__ h2,
    const float* __restrict__ wc, const float* __restrict__ bc,
    const float* __restrict__ wb, const float* __restrict__ bb,
    float* __restrict__ out)
{
    const int gw   = (blockIdx.x * 256 + threadIdx.x) >> 6;
    const int lane = threadIdx.x & 63;
    const float* hrow = h2 + (size_t)gw * HID;

    float4 h[4];
#pragma unroll
    for (int j = 0; j < 4; ++j)
        h[j] = *(const float4*)(hrow + lane * 16 + j * 4);

    float keep = 0.0f;
#pragma unroll
    for (int o = 0; o < 10; ++o) {
        const float* wrow = (o < 2) ? (wc + (size_t)o * HID)
                                    : (wb + (size_t)(o - 2) * HID);
        float acc = 0.0f;
#pragma unroll
        for (int j = 0; j < 4; ++j) {
            const float4 w4 = *(const float4*)(wrow + lane * 16 + j * 4);
            acc += h[j].x * w4.x + h[j].y * w4.y + h[j].z * w4.z + h[j].w * w4.w;
        }
#pragma unroll
        for (int s = 32; s; s >>= 1) acc += __shfl_xor(acc, s, 64);
        if (lane == o) keep = acc;
    }
    if (lane < 2)        out[gw * 2 + lane] = keep + bc[lane];
    else if (lane < 10)  out[NROI * 2 + gw * 8 + (lane - 2)] = keep + bb[lane - 2];
}

// ---------------------------------------------------------------------------
extern "C" void kernel_launch(void* const* d_in, const int* in_sizes, int n_in,
                              void* d_out, int out_size, void* d_ws, size_t ws_size,
                              hipStream_t stream)
{
    const float* x    = (const float*)d_in[0];
    const float* rois = (const float*)d_in[1];
    const float* w1   = (const float*)d_in[2];
    const float* b1   = (const float*)d_in[3];
    const float* w2   = (const float*)d_in[4];
    const float* b2   = (const float*)d_in[5];
    const float* wc   = (const float*)d_in[6];
    const float* bc   = (const float*)d_in[7];
    const float* wb   = (const float*)d_in[8];
    const float* bb   = (const float*)d_in[9];
    float* out = (float*)d_out;

    char* ws = (char*)d_ws;
    const size_t CRB = (size_t)NROI * FANIN * 2;     // 51,380,224
    const size_t W1B = (size_t)HID * FANIN * 2;      // 25,690,112
    const size_t W2B = (size_t)HID * HID * 2;        //  2,097,152
    const size_t PB  = (size_t)NROI * HID * 4;       //  8,388,608 per z-slice
    const size_t HB  = (size_t)NROI * HID * 2;       //  4,194,304
    const size_t GXB = (size_t)NROI * 7 * 8;         //    114,688
    const size_t LSB = (size_t)4 * NROI * 4;         //     32,768

    const int Z1 = 8;   // FC1 K-split: 12544/8 = 1568 (49 K-steps)
    const int Z2 = 4;   // FC2 K-split: 1024/4  = 256  (8 K-steps)

    size_t off = 0;
    _Float16* cropsF = (_Float16*)(ws + off); off += CRB;
    _Float16* w1F    = (_Float16*)(ws + off); off += W1B;
    _Float16* w2F    = (_Float16*)(ws + off); off += W2B;
    float*    P      = (float*)(ws + off);    off += (size_t)Z1 * PB;
    _Float16* h1F    = (_Float16*)(ws + off); off += HB;
    uint2*    geomX  = (uint2*)(ws + off);    off += GXB;
    uint2*    geomY  = (uint2*)(ws + off);    off += GXB;
    int*      list   = (int*)(ws + off);      off += LSB;
    int*      cnt    = (int*)(ws + off);      off += 64;
    float*    h2     = P;   // elementwise alias with P[0] in combine_relu_f32

    // ROI geometry + per-image lists
    zero_cnt_kernel<<<1, 64, 0, stream>>>(cnt);
    roi_geom_kernel<<<NROI / 256, 256, 0, stream>>>(rois, geomX, geomY, list, cnt);

    // weight conversions
    convert_f16<<<2048, 256, 0, stream>>>(w1, w1F, HID * FANIN / 4);
    convert_f16<<<1024, 256, 0, stream>>>(w2, w2F, HID * HID / 4);

    // RoIAlign: block per (channel, image), slab in LDS
    roi_align_kernel<<<dim3(CCH, 4), 1024, 0, stream>>>(
        x, geomX, geomY, list, cnt, cropsF);

    // FC1: K = 12544
    gemm_f16<<<dim3(HID / 128, NROI / 128, Z1), 256, 0, stream>>>(
        cropsF, w1F, P, NROI, HID, FANIN, FANIN / Z1);
    combine_relu_f16<<<(NROI * HID / 4) / 256, 256, 0, stream>>>(P, Z1, b1, h1F);

    // FC2: K = 1024
    gemm_f16<<<dim3(HID / 128, NROI / 128, Z2), 256, 0, stream>>>(
        h1F, w2F, P, NROI, HID, HID, HID / Z2);
    combine_relu_f32<<<(NROI * HID / 4) / 256, 256, 0, stream>>>(P, Z2, b2, h2);

    // heads
    heads_kernel<<<NROI / 4, 256, 0, stream>>>(h2, wc, bc, wb, bb, out);
}